// Round 7
// baseline (94.389 us; speedup 1.0000x reference)
//
#include <hip/hip_runtime.h>

// SharedMultiCategoricalEncoder on MI355X — round 7: max-occupancy variant.
// x: [B=8192, C=32, L=8] int32 ids in [0, 9311); emb: [9311, 64] fp32 (row 0 zeros).
// out[b,c,:] = sum_l emb[x[b,c,l]] / max(#(x[b,c,l] > 0), 1)
//
// Evidence: R5 (16 outstanding/thread, 4 waves/SIMD) -5.7us; R6 (pipelined,
// same occupancy) flat => per-wave MLP saturated. Untested axis: wave count.
// This kernel keeps 8 outstanding gathers/thread but halves VGPRs (<=64 via
// __launch_bounds__(256,8)) so 8 waves/SIMD are resident: same 64 outstanding
// lines per SIMD as R5, but 2x the wave-level overlap of the dependent
// phases (id-load latency, store drain).

#define NPAIRS (8192 * 32)          // B*C = 262144
#define LL 8
#define NROWS 9311
#define D 64
#define TAB_ELEMS (NROWS * D)       // 595,904

typedef float  vfloat4 __attribute__((ext_vector_type(4)));
typedef int    vint4   __attribute__((ext_vector_type(4)));
typedef unsigned int  uint32;
typedef unsigned int  vuint4 __attribute__((ext_vector_type(4)));
typedef unsigned short vushort4 __attribute__((ext_vector_type(4)));

// ---- prologue: fp32 table -> bf16 (round-to-nearest-even) ------------------
__global__ __launch_bounds__(256) void
cvt_table_bf16(const vfloat4* __restrict__ src, vushort4* __restrict__ dst, int n4) {
    const int i = blockIdx.x * blockDim.x + threadIdx.x;
    if (i >= n4) return;
    const vfloat4 f = src[i];
    vushort4 o;
    #pragma unroll
    for (int k = 0; k < 4; ++k) {
        uint32 b = __float_as_uint(f[k]);
        b = (b + 0x7fff + ((b >> 16) & 1)) >> 16;   // RNE (inputs finite)
        o[k] = (unsigned short)b;
    }
    dst[i] = o;
}

// ---- main: 8 lanes/pair, 1 pair/thread, 8 waves/SIMD -----------------------
__global__ __launch_bounds__(256, 8) void
SharedMultiCategoricalEncoder_kernel(const int* __restrict__ x,
                                     const vuint4* __restrict__ tab,   // bf16 table
                                     vfloat4* __restrict__ out4) {
    const int tid  = blockIdx.x * blockDim.x + threadIdx.x;
    const int pair = tid >> 3;
    const int sub  = tid & 7;              // channel chunk [sub*8, sub*8+8)

    const vint4* xp = (const vint4*)(x + pair * LL);
    const vint4 i01 = xp[0];
    const vint4 i23 = xp[1];
    const int ids[LL] = { i01.x, i01.y, i01.z, i01.w,
                          i23.x, i23.y, i23.z, i23.w };

    // All 8 gathers in flight before any consumption (8 x dwordx4 = 32 VGPRs).
    vuint4 e[LL];
#pragma unroll
    for (int l = 0; l < LL; ++l) e[l] = tab[ids[l] * 8 + sub];

    int cnt = 0;
#pragma unroll
    for (int l = 0; l < LL; ++l) cnt += (ids[l] > 0);

    float acc[8] = {0.f};
#pragma unroll
    for (int l = 0; l < LL; ++l) {
        #pragma unroll
        for (int q = 0; q < 4; ++q) {
            const uint32 u = e[l][q];
            acc[2*q]   += __uint_as_float(u << 16);
            acc[2*q+1] += __uint_as_float(u & 0xffff0000u);
        }
    }

    const float s = 1.0f / (float)(cnt > 0 ? cnt : 1);
    vfloat4* op = out4 + pair * 16 + sub * 2;
    op[0] = (vfloat4){acc[0], acc[1], acc[2], acc[3]} * s;
    op[1] = (vfloat4){acc[4], acc[5], acc[6], acc[7]} * s;
}

extern "C" void kernel_launch(void* const* d_in, const int* in_sizes, int n_in,
                              void* d_out, int out_size, void* d_ws, size_t ws_size,
                              hipStream_t stream) {
    const int*   x   = (const int*)d_in[0];
    const float* emb = (const float*)d_in[1];
    float*       out = (float*)d_out;

    // bf16 table in workspace: 9311*64*2 B = 1.19 MB.
    const int n4 = TAB_ELEMS / 4;
    cvt_table_bf16<<<(n4 + 255) / 256, 256, 0, stream>>>(
        (const vfloat4*)emb, (vushort4*)d_ws, n4);

    const int threads = 256;
    const int blocks  = (NPAIRS * 8) / threads;   // 8192 blocks, 2.1M threads
    SharedMultiCategoricalEncoder_kernel<<<blocks, threads, 0, stream>>>(
        x, (const vuint4*)d_ws, (vfloat4*)out);
}